// Round 3
// baseline (874.074 us; speedup 1.0000x reference)
//
#include <hip/hip_runtime.h>

// Fused 16-expert, 2-layer Linear+ReLU stack, v4 (persistent, sY eliminated).
//   x  [524288, 128] fp32 -> 16 slices of 32768 tokens
//   W  [16, 2, 128, 128] fp32 (torch [out,in]) ; b [16, 2, 128] fp32
//
// v4 strategy:
//  - layer 1: D = W0_frag(16x16x32 A) x x_frag -> thread (ln,q) owns
//    y[token ln][feature gt*16+q*4+r], r=0..3.
//  - layer 2 uses mfma_f32_16x16x16bf16_1k: its B-operand layout is
//    lane (ln,q) -> col=ln, k=q*4..q*4+3 == EXACTLY layer-1's D layout.
//    So yb[gtk] = pack4(relu(acc[gtk])) feeds layer 2 straight from
//    registers: NO sY LDS buffer, no fences, no cross-lane exchange.
//  - W1 stored k-pair-packed ([gt2][ktp][lane][gtk&1][4]): one ds_read_b128
//    feeds two 16x16x16 MFMAs.
//  - LDS = 32K(W0)+32K(W1)+1K(sB) = 65KB -> 2 blocks/CU = 16 waves/CU,
//    512 persistent blocks = exactly one resident generation.
//  - one __syncthreads total (post W-staging); x prefetched a full tile ahead.

#define NF    128
#define NM    16
#define NTOK  524288
#define TPM   (NTOK / NM)      // 32768 tokens per model
#define BM    128              // tokens per tile
#define TILES 8                // tiles per block
#define BLKPM ((TPM / BM) / TILES)   // 32 blocks per model

typedef __attribute__((ext_vector_type(8))) short bf16x8;
typedef __attribute__((ext_vector_type(4))) short bf16x4v;
typedef __attribute__((ext_vector_type(4))) float f32x4;
typedef unsigned int u32;

__device__ __forceinline__ unsigned short f2bf(float f) {
    union { float f; unsigned u; } v; v.f = f;
    unsigned r = v.u + 0x7FFFu + ((v.u >> 16) & 1u);   // RNE
    return (unsigned short)(r >> 16);
}

// bf16 W in fragment-major layout, per model:
//  layer 0 chunk fid=gt*4+kt : [lane][e] , e: k = kt*32 + (lane>>4)*8 + e
//  layer 1 chunk fid=gt2*4+ktp: [lane][e] , e: k = ktp*32 + (e>>2)*16 + (lane>>4)*4 + (e&3)
__device__ alignas(16) unsigned short g_Wf[NM * 2 * NF * NF];   // 1 MiB

__global__ __launch_bounds__(256) void convw_kernel(const float* __restrict__ W) {
    const int idx  = blockIdx.x * 256 + threadIdx.x;  // 65536 fragment-lanes
    const int lane = idx & 63;
    const int q    = lane >> 4;
    const int fid  = (idx >> 6) & 31;
    const int ml   = idx >> 11;                       // m*2 + l
    const int row  = (fid >> 2) * 16 + (lane & 15);   // out-feature
    const float* base = W + ((size_t)ml * NF + row) * NF;
    int c0, c1;
    if (ml & 1) { c0 = (fid & 3) * 32 + q * 4; c1 = c0 + 16; }  // 16x16x16 A, k-pair-packed
    else        { c0 = (fid & 3) * 32 + q * 8; c1 = c0 + 4;  }  // 16x16x32 A
    float4 a = *(const float4*)(base + c0);
    float4 c = *(const float4*)(base + c1);
    unsigned short* d = &g_Wf[(size_t)idx * 8];
    d[0] = f2bf(a.x); d[1] = f2bf(a.y); d[2] = f2bf(a.z); d[3] = f2bf(a.w);
    d[4] = f2bf(c.x); d[5] = f2bf(c.y); d[6] = f2bf(c.z); d[7] = f2bf(c.w);
}

__device__ __forceinline__ void load_lds16(const unsigned short* g, unsigned short* l) {
    __builtin_amdgcn_global_load_lds(
        (const __attribute__((address_space(1))) u32*)g,
        (__attribute__((address_space(3))) u32*)l, 16, 0, 0);
}

__global__ __launch_bounds__(512, 4) void mlp16_kernel(
        const float* __restrict__ x, const float* __restrict__ b,
        float* __restrict__ out) {
    __shared__ alignas(16) unsigned short sW0[NF * NF];   // 32768 B
    __shared__ alignas(16) unsigned short sW1[NF * NF];   // 32768 B
    __shared__ alignas(16) float sB[2 * NF];              // 1024 B

    const int t    = threadIdx.x;
    const int w    = t >> 6;       // wave 0..7, owns tokens w*16..w*16+15
    const int lane = t & 63;
    const int ln   = lane & 15;    // token within wave's 16-group
    const int q    = lane >> 4;    // k-group / feature-quad select

    const int m  = blockIdx.x / BLKPM;
    const int tg = blockIdx.x % BLKPM;

    if (t < 2 * NF) sB[t] = b[m * 2 * NF + t];

    // ---- stage W0 + W1 fragments once (wave w: fids w*4..w*4+3) ----
    const unsigned short* wsrc = g_Wf + (size_t)m * 2 * NF * NF;
    #pragma unroll
    for (int i = 0; i < 4; ++i) {
        const int fid = w * 4 + i;
        load_lds16(wsrc + (size_t)(fid * 64 + lane) * 8, &sW0[fid * 512]);
        load_lds16(wsrc + NF * NF + (size_t)(fid * 64 + lane) * 8, &sW1[fid * 512]);
    }

    const size_t tok0 = (size_t)m * TPM + (size_t)tg * (TILES * BM);
    const float* xrow = x + (tok0 + (size_t)(w * 16 + ln)) * NF;
    float*       orow = out + (tok0 + (size_t)(w * 16 + ln)) * NF;

    // ---- prefetch tile 0 x into regs (hides W staging latency) ----
    float4 xa[8];
    #pragma unroll
    for (int kt = 0; kt < 4; ++kt) {
        xa[2 * kt]     = *(const float4*)(xrow + kt * 32 + q * 8);
        xa[2 * kt + 1] = *(const float4*)(xrow + kt * 32 + q * 8 + 4);
    }

    __syncthreads();   // the ONLY barrier: W/sB staging complete

    for (int i = 0; i < TILES; ++i) {
        // -- convert tile-i x to bf16 fragments (frees xa) --
        bf16x8 xb[4];
        #pragma unroll
        for (int kt = 0; kt < 4; ++kt) {
            const float4 a0 = xa[2 * kt], a1 = xa[2 * kt + 1];
            bf16x8 v;
            v[0] = (short)f2bf(a0.x); v[1] = (short)f2bf(a0.y);
            v[2] = (short)f2bf(a0.z); v[3] = (short)f2bf(a0.w);
            v[4] = (short)f2bf(a1.x); v[5] = (short)f2bf(a1.y);
            v[6] = (short)f2bf(a1.z); v[7] = (short)f2bf(a1.w);
            xb[kt] = v;
        }

        // -- issue tile i+1 x loads (covered by this tile's compute) --
        if (i + 1 < TILES) {
            const float* p = xrow + (size_t)(i + 1) * (BM * NF);
            #pragma unroll
            for (int kt = 0; kt < 4; ++kt) {
                xa[2 * kt]     = *(const float4*)(p + kt * 32 + q * 8);
                xa[2 * kt + 1] = *(const float4*)(p + kt * 32 + q * 8 + 4);
            }
        }

        // -- layer 1: A = W0 fragment (16x16x32), B = x fragment, C-in = bias --
        f32x4 acc[8];
        #pragma unroll
        for (int gt = 0; gt < 8; ++gt) acc[gt] = *(const f32x4*)&sB[gt * 16 + q * 4];
        #pragma unroll
        for (int kt = 0; kt < 4; ++kt) {
            #pragma unroll
            for (int gt = 0; gt < 8; ++gt) {
                bf16x8 wf = *(const bf16x8*)&sW0[((gt * 4 + kt) * 64 + lane) * 8];
                acc[gt] = __builtin_amdgcn_mfma_f32_16x16x32_bf16(wf, xb[kt], acc[gt], 0, 0, 0);
            }
        }

        // -- relu + pack: layer-1 D layout == 16x16x16 B layout, in-register --
        bf16x4v yb[8];
        #pragma unroll
        for (int gtk = 0; gtk < 8; ++gtk) {
            bf16x4v yv;
            #pragma unroll
            for (int r = 0; r < 4; ++r) {
                float vv = acc[gtk][r];
                vv = vv > 0.f ? vv : 0.f;
                yv[r] = (short)f2bf(vv);
            }
            yb[gtk] = yv;
        }

        // -- layer 2: A = W1 fragment (16x16x16 pair), B = yb, C-in = bias --
        f32x4 acc2[8];
        #pragma unroll
        for (int gt = 0; gt < 8; ++gt) acc2[gt] = *(const f32x4*)&sB[NF + gt * 16 + q * 4];
        #pragma unroll
        for (int ktp = 0; ktp < 4; ++ktp) {
            #pragma unroll
            for (int gt2 = 0; gt2 < 8; ++gt2) {
                bf16x8 wf = *(const bf16x8*)&sW1[((gt2 * 4 + ktp) * 64 + lane) * 8];
                bf16x4v lo = __builtin_shufflevector(wf, wf, 0, 1, 2, 3);
                bf16x4v hi = __builtin_shufflevector(wf, wf, 4, 5, 6, 7);
                acc2[gt2] = __builtin_amdgcn_mfma_f32_16x16x16bf16_1k(lo, yb[2 * ktp],     acc2[gt2], 0, 0, 0);
                acc2[gt2] = __builtin_amdgcn_mfma_f32_16x16x16bf16_1k(hi, yb[2 * ktp + 1], acc2[gt2], 0, 0, 0);
            }
        }

        // -- relu -> global out: coalesced float4 per gt --
        float* op = orow + (size_t)i * (BM * NF);
        #pragma unroll
        for (int gt = 0; gt < 8; ++gt) {
            float4 o;
            float v0 = acc2[gt][0]; o.x = v0 > 0.f ? v0 : 0.f;
            float v1 = acc2[gt][1]; o.y = v1 > 0.f ? v1 : 0.f;
            float v2 = acc2[gt][2]; o.z = v2 > 0.f ? v2 : 0.f;
            float v3 = acc2[gt][3]; o.w = v3 > 0.f ? v3 : 0.f;
            *(float4*)(op + gt * 16 + q * 4) = o;
        }
    }
}

extern "C" void kernel_launch(void* const* d_in, const int* in_sizes, int n_in,
                              void* d_out, int out_size, void* d_ws, size_t ws_size,
                              hipStream_t stream) {
    const float* x = (const float*)d_in[0];
    const float* W = (const float*)d_in[1];
    const float* b = (const float*)d_in[2];
    float* out = (float*)d_out;
    convw_kernel<<<dim3(256), dim3(256), 0, stream>>>(W);
    mlp16_kernel<<<dim3(NM * BLKPM), dim3(512), 0, stream>>>(x, b, out);
}

// Round 4
// 570.546 us; speedup vs baseline: 1.5320x; 1.5320x over previous
//
#include <hip/hip_runtime.h>

// Fused 16-expert, 2-layer Linear+ReLU stack, v4b (persistent, sY eliminated,
// spill-free occupancy contract).
//   x  [524288, 128] fp32 -> 16 slices of 32768 tokens
//   W  [16, 2, 128, 128] fp32 (torch [out,in]) ; b [16, 2, 128] fp32
//
// v4b = v4 with __launch_bounds__(512, 2):
//  v4's (512,4) was interpreted as 4 blocks/CU -> 8 waves/EU -> 64-VGPR cap,
//  which spilled the ~110-reg body to scratch (FETCH 1.1GB, WRITE 576MB,
//  574us). (512,2) -> 128-VGPR cap under either interpretation; body fits,
//  LDS (65KB) and VGPR both allow 2 blocks/CU = 16 waves/CU.
//
//  - layer 1: D = W0_frag(16x16x32 A) x x_frag -> thread (ln,q) owns
//    y[token ln][feature gt*16+q*4+r], r=0..3.
//  - layer 2 uses mfma_f32_16x16x16bf16_1k: its B-operand layout is
//    lane (ln,q) -> col=ln, k=q*4..q*4+3 == EXACTLY layer-1's D layout.
//    So yb[gtk] = pack4(relu(acc[gtk])) feeds layer 2 straight from
//    registers: NO sY LDS buffer, no fences, no cross-lane exchange.
//  - W1 stored k-pair-packed: one ds_read_b128 feeds two 16x16x16 MFMAs.
//  - one __syncthreads total; x prefetched a full tile ahead.

#define NF    128
#define NM    16
#define NTOK  524288
#define TPM   (NTOK / NM)      // 32768 tokens per model
#define BM    128              // tokens per tile
#define TILES 8                // tiles per block
#define BLKPM ((TPM / BM) / TILES)   // 32 blocks per model

typedef __attribute__((ext_vector_type(8))) short bf16x8;
typedef __attribute__((ext_vector_type(4))) short bf16x4v;
typedef __attribute__((ext_vector_type(4))) float f32x4;
typedef unsigned int u32;

__device__ __forceinline__ unsigned short f2bf(float f) {
    union { float f; unsigned u; } v; v.f = f;
    unsigned r = v.u + 0x7FFFu + ((v.u >> 16) & 1u);   // RNE
    return (unsigned short)(r >> 16);
}

// bf16 W in fragment-major layout, per model:
//  layer 0 chunk fid=gt*4+kt : [lane][e] , e: k = kt*32 + (lane>>4)*8 + e
//  layer 1 chunk fid=gt2*4+ktp: [lane][e] , e: k = ktp*32 + (e>>2)*16 + (lane>>4)*4 + (e&3)
__device__ alignas(16) unsigned short g_Wf[NM * 2 * NF * NF];   // 1 MiB

__global__ __launch_bounds__(256) void convw_kernel(const float* __restrict__ W) {
    const int idx  = blockIdx.x * 256 + threadIdx.x;  // 65536 fragment-lanes
    const int lane = idx & 63;
    const int q    = lane >> 4;
    const int fid  = (idx >> 6) & 31;
    const int ml   = idx >> 11;                       // m*2 + l
    const int row  = (fid >> 2) * 16 + (lane & 15);   // out-feature
    const float* base = W + ((size_t)ml * NF + row) * NF;
    int c0, c1;
    if (ml & 1) { c0 = (fid & 3) * 32 + q * 4; c1 = c0 + 16; }  // 16x16x16 A, k-pair-packed
    else        { c0 = (fid & 3) * 32 + q * 8; c1 = c0 + 4;  }  // 16x16x32 A
    float4 a = *(const float4*)(base + c0);
    float4 c = *(const float4*)(base + c1);
    unsigned short* d = &g_Wf[(size_t)idx * 8];
    d[0] = f2bf(a.x); d[1] = f2bf(a.y); d[2] = f2bf(a.z); d[3] = f2bf(a.w);
    d[4] = f2bf(c.x); d[5] = f2bf(c.y); d[6] = f2bf(c.z); d[7] = f2bf(c.w);
}

__device__ __forceinline__ void load_lds16(const unsigned short* g, unsigned short* l) {
    __builtin_amdgcn_global_load_lds(
        (const __attribute__((address_space(1))) u32*)g,
        (__attribute__((address_space(3))) u32*)l, 16, 0, 0);
}

__global__ __launch_bounds__(512, 2) void mlp16_kernel(
        const float* __restrict__ x, const float* __restrict__ b,
        float* __restrict__ out) {
    __shared__ alignas(16) unsigned short sW0[NF * NF];   // 32768 B
    __shared__ alignas(16) unsigned short sW1[NF * NF];   // 32768 B
    __shared__ alignas(16) float sB[2 * NF];              // 1024 B

    const int t    = threadIdx.x;
    const int w    = t >> 6;       // wave 0..7, owns tokens w*16..w*16+15
    const int lane = t & 63;
    const int ln   = lane & 15;    // token within wave's 16-group
    const int q    = lane >> 4;    // k-group / feature-quad select

    const int m  = blockIdx.x / BLKPM;
    const int tg = blockIdx.x % BLKPM;

    if (t < 2 * NF) sB[t] = b[m * 2 * NF + t];

    // ---- stage W0 + W1 fragments once (wave w: fids w*4..w*4+3) ----
    const unsigned short* wsrc = g_Wf + (size_t)m * 2 * NF * NF;
    #pragma unroll
    for (int i = 0; i < 4; ++i) {
        const int fid = w * 4 + i;
        load_lds16(wsrc + (size_t)(fid * 64 + lane) * 8, &sW0[fid * 512]);
        load_lds16(wsrc + NF * NF + (size_t)(fid * 64 + lane) * 8, &sW1[fid * 512]);
    }

    const size_t tok0 = (size_t)m * TPM + (size_t)tg * (TILES * BM);
    const float* xrow = x + (tok0 + (size_t)(w * 16 + ln)) * NF;
    float*       orow = out + (tok0 + (size_t)(w * 16 + ln)) * NF;

    // ---- prefetch tile 0 x into regs (hides W staging latency) ----
    float4 xa[8];
    #pragma unroll
    for (int kt = 0; kt < 4; ++kt) {
        xa[2 * kt]     = *(const float4*)(xrow + kt * 32 + q * 8);
        xa[2 * kt + 1] = *(const float4*)(xrow + kt * 32 + q * 8 + 4);
    }

    __syncthreads();   // the ONLY barrier: W/sB staging complete

    for (int i = 0; i < TILES; ++i) {
        // -- convert tile-i x to bf16 fragments (frees xa) --
        bf16x8 xb[4];
        #pragma unroll
        for (int kt = 0; kt < 4; ++kt) {
            const float4 a0 = xa[2 * kt], a1 = xa[2 * kt + 1];
            bf16x8 v;
            v[0] = (short)f2bf(a0.x); v[1] = (short)f2bf(a0.y);
            v[2] = (short)f2bf(a0.z); v[3] = (short)f2bf(a0.w);
            v[4] = (short)f2bf(a1.x); v[5] = (short)f2bf(a1.y);
            v[6] = (short)f2bf(a1.z); v[7] = (short)f2bf(a1.w);
            xb[kt] = v;
        }

        // -- issue tile i+1 x loads (covered by this tile's compute) --
        if (i + 1 < TILES) {
            const float* p = xrow + (size_t)(i + 1) * (BM * NF);
            #pragma unroll
            for (int kt = 0; kt < 4; ++kt) {
                xa[2 * kt]     = *(const float4*)(p + kt * 32 + q * 8);
                xa[2 * kt + 1] = *(const float4*)(p + kt * 32 + q * 8 + 4);
            }
        }

        // -- layer 1: A = W0 fragment (16x16x32), B = x fragment, C-in = bias --
        f32x4 acc[8];
        #pragma unroll
        for (int gt = 0; gt < 8; ++gt) acc[gt] = *(const f32x4*)&sB[gt * 16 + q * 4];
        #pragma unroll
        for (int kt = 0; kt < 4; ++kt) {
            #pragma unroll
            for (int gt = 0; gt < 8; ++gt) {
                bf16x8 wf = *(const bf16x8*)&sW0[((gt * 4 + kt) * 64 + lane) * 8];
                acc[gt] = __builtin_amdgcn_mfma_f32_16x16x32_bf16(wf, xb[kt], acc[gt], 0, 0, 0);
            }
        }

        // -- relu + pack: layer-1 D layout == 16x16x16 B layout, in-register --
        bf16x4v yb[8];
        #pragma unroll
        for (int gtk = 0; gtk < 8; ++gtk) {
            bf16x4v yv;
            #pragma unroll
            for (int r = 0; r < 4; ++r) {
                float vv = acc[gtk][r];
                vv = vv > 0.f ? vv : 0.f;
                yv[r] = (short)f2bf(vv);
            }
            yb[gtk] = yv;
        }

        // -- layer 2: A = W1 fragment (16x16x16 pair), B = yb, C-in = bias --
        f32x4 acc2[8];
        #pragma unroll
        for (int gt = 0; gt < 8; ++gt) acc2[gt] = *(const f32x4*)&sB[NF + gt * 16 + q * 4];
        #pragma unroll
        for (int ktp = 0; ktp < 4; ++ktp) {
            #pragma unroll
            for (int gt2 = 0; gt2 < 8; ++gt2) {
                bf16x8 wf = *(const bf16x8*)&sW1[((gt2 * 4 + ktp) * 64 + lane) * 8];
                bf16x4v lo = __builtin_shufflevector(wf, wf, 0, 1, 2, 3);
                bf16x4v hi = __builtin_shufflevector(wf, wf, 4, 5, 6, 7);
                acc2[gt2] = __builtin_amdgcn_mfma_f32_16x16x16bf16_1k(lo, yb[2 * ktp],     acc2[gt2], 0, 0, 0);
                acc2[gt2] = __builtin_amdgcn_mfma_f32_16x16x16bf16_1k(hi, yb[2 * ktp + 1], acc2[gt2], 0, 0, 0);
            }
        }

        // -- relu -> global out: coalesced float4 per gt --
        float* op = orow + (size_t)i * (BM * NF);
        #pragma unroll
        for (int gt = 0; gt < 8; ++gt) {
            float4 o;
            float v0 = acc2[gt][0]; o.x = v0 > 0.f ? v0 : 0.f;
            float v1 = acc2[gt][1]; o.y = v1 > 0.f ? v1 : 0.f;
            float v2 = acc2[gt][2]; o.z = v2 > 0.f ? v2 : 0.f;
            float v3 = acc2[gt][3]; o.w = v3 > 0.f ? v3 : 0.f;
            *(float4*)(op + gt * 16 + q * 4) = o;
        }
    }
}

extern "C" void kernel_launch(void* const* d_in, const int* in_sizes, int n_in,
                              void* d_out, int out_size, void* d_ws, size_t ws_size,
                              hipStream_t stream) {
    const float* x = (const float*)d_in[0];
    const float* W = (const float*)d_in[1];
    const float* b = (const float*)d_in[2];
    float* out = (float*)d_out;
    convw_kernel<<<dim3(256), dim3(256), 0, stream>>>(W);
    mlp16_kernel<<<dim3(NM * BLKPM), dim3(512), 0, stream>>>(x, b, out);
}

// Round 5
// 453.203 us; speedup vs baseline: 1.9287x; 1.2589x over previous
//
#include <hip/hip_runtime.h>

// Fused 16-expert, 2-layer Linear+ReLU stack, v5 (persistent, sY eliminated,
// spill-free: LICM of loop-invariant LDS loads blocked).
//   x  [524288, 128] fp32 -> 16 slices of 32768 tokens
//   W  [16, 2, 128, 128] fp32 (torch [out,in]) ; b [16, 2, 128] fp32
//
// v5 = v4b + anti-hoist laundering:
//  v4b capped VGPR at 128 (launch_bounds 2nd arg == blocks/CU on this hipcc:
//  (512,4)->64, (512,2)->128 measured) but still spilled ~16 regs/tile
//  (FETCH 639MB / WRITE 403MB vs ~290/268 ideal). Cause: all W-fragment and
//  bias LDS reads in the tile loop are loop-invariant -> LICM hoists them
//  into long-lived registers, pushing loop-carried state (xa prefetch) into
//  scratch. Fix: opaque zoff=0 (asm) added to the LDS bases each iteration
//  makes those loads non-invariant; plus #pragma unroll 1 on the tile loop.
//
//  - layer 1: D = W0_frag(16x16x32 A) x x_frag -> thread (ln,q) owns
//    y[token ln][feature gt*16+q*4+r], r=0..3.
//  - layer 2 uses mfma_f32_16x16x16bf16_1k: its B-operand layout ==
//    layer-1's D layout, so relu+pack feeds layer 2 from registers
//    (no sY LDS buffer, no barriers in the loop).
//  - W1 k-pair-packed: one ds_read_b128 feeds two 16x16x16 MFMAs.
//  - LDS 65KB -> 2 blocks/CU = 16 waves/CU; one __syncthreads total.

#define NF    128
#define NM    16
#define NTOK  524288
#define TPM   (NTOK / NM)      // 32768 tokens per model
#define BM    128              // tokens per tile
#define TILES 8                // tiles per block
#define BLKPM ((TPM / BM) / TILES)   // 32 blocks per model

typedef __attribute__((ext_vector_type(8))) short bf16x8;
typedef __attribute__((ext_vector_type(4))) short bf16x4v;
typedef __attribute__((ext_vector_type(4))) float f32x4;
typedef unsigned int u32;

__device__ __forceinline__ unsigned short f2bf(float f) {
    union { float f; unsigned u; } v; v.f = f;
    unsigned r = v.u + 0x7FFFu + ((v.u >> 16) & 1u);   // RNE
    return (unsigned short)(r >> 16);
}

// bf16 W in fragment-major layout, per model:
//  layer 0 chunk fid=gt*4+kt : [lane][e] , e: k = kt*32 + (lane>>4)*8 + e
//  layer 1 chunk fid=gt2*4+ktp: [lane][e] , e: k = ktp*32 + (e>>2)*16 + (lane>>4)*4 + (e&3)
__device__ alignas(16) unsigned short g_Wf[NM * 2 * NF * NF];   // 1 MiB

__global__ __launch_bounds__(256) void convw_kernel(const float* __restrict__ W) {
    const int idx  = blockIdx.x * 256 + threadIdx.x;  // 65536 fragment-lanes
    const int lane = idx & 63;
    const int q    = lane >> 4;
    const int fid  = (idx >> 6) & 31;
    const int ml   = idx >> 11;                       // m*2 + l
    const int row  = (fid >> 2) * 16 + (lane & 15);   // out-feature
    const float* base = W + ((size_t)ml * NF + row) * NF;
    int c0, c1;
    if (ml & 1) { c0 = (fid & 3) * 32 + q * 4; c1 = c0 + 16; }  // 16x16x16 A, k-pair-packed
    else        { c0 = (fid & 3) * 32 + q * 8; c1 = c0 + 4;  }  // 16x16x32 A
    float4 a = *(const float4*)(base + c0);
    float4 c = *(const float4*)(base + c1);
    unsigned short* d = &g_Wf[(size_t)idx * 8];
    d[0] = f2bf(a.x); d[1] = f2bf(a.y); d[2] = f2bf(a.z); d[3] = f2bf(a.w);
    d[4] = f2bf(c.x); d[5] = f2bf(c.y); d[6] = f2bf(c.z); d[7] = f2bf(c.w);
}

__device__ __forceinline__ void load_lds16(const unsigned short* g, unsigned short* l) {
    __builtin_amdgcn_global_load_lds(
        (const __attribute__((address_space(1))) u32*)g,
        (__attribute__((address_space(3))) u32*)l, 16, 0, 0);
}

__global__ __launch_bounds__(512, 2) void mlp16_kernel(
        const float* __restrict__ x, const float* __restrict__ b,
        float* __restrict__ out) {
    __shared__ alignas(16) unsigned short sW0[NF * NF];   // 32768 B
    __shared__ alignas(16) unsigned short sW1[NF * NF];   // 32768 B
    __shared__ alignas(16) float sB[2 * NF];              // 1024 B

    const int t    = threadIdx.x;
    const int w    = t >> 6;       // wave 0..7, owns tokens w*16..w*16+15
    const int lane = t & 63;
    const int ln   = lane & 15;    // token within wave's 16-group
    const int q    = lane >> 4;    // k-group / feature-quad select

    const int m  = blockIdx.x / BLKPM;
    const int tg = blockIdx.x % BLKPM;

    if (t < 2 * NF) sB[t] = b[m * 2 * NF + t];

    // ---- stage W0 + W1 fragments once (wave w: fids w*4..w*4+3) ----
    const unsigned short* wsrc = g_Wf + (size_t)m * 2 * NF * NF;
    #pragma unroll
    for (int i = 0; i < 4; ++i) {
        const int fid = w * 4 + i;
        load_lds16(wsrc + (size_t)(fid * 64 + lane) * 8, &sW0[fid * 512]);
        load_lds16(wsrc + NF * NF + (size_t)(fid * 64 + lane) * 8, &sW1[fid * 512]);
    }

    const size_t tok0 = (size_t)m * TPM + (size_t)tg * (TILES * BM);
    const float* xrow = x + (tok0 + (size_t)(w * 16 + ln)) * NF;
    float*       orow = out + (tok0 + (size_t)(w * 16 + ln)) * NF;

    // ---- prefetch tile 0 x into regs (hides W staging latency) ----
    float4 xa[8];
    #pragma unroll
    for (int kt = 0; kt < 4; ++kt) {
        xa[2 * kt]     = *(const float4*)(xrow + kt * 32 + q * 8);
        xa[2 * kt + 1] = *(const float4*)(xrow + kt * 32 + q * 8 + 4);
    }

    __syncthreads();   // the ONLY barrier: W/sB staging complete

    #pragma unroll 1
    for (int i = 0; i < TILES; ++i) {
        // opaque zero: makes all LDS operand loads loop-VARIANT so LICM
        // cannot hoist them into long-lived registers (the v4b spill cause)
        int zoff = 0;
        asm volatile("" : "+v"(zoff));
        const unsigned short* w0p = sW0 + zoff;
        const unsigned short* w1p = sW1 + zoff;
        const float*          bp  = sB + zoff;

        // -- convert tile-i x to bf16 fragments (frees xa) --
        bf16x8 xb[4];
        #pragma unroll
        for (int kt = 0; kt < 4; ++kt) {
            const float4 a0 = xa[2 * kt], a1 = xa[2 * kt + 1];
            bf16x8 v;
            v[0] = (short)f2bf(a0.x); v[1] = (short)f2bf(a0.y);
            v[2] = (short)f2bf(a0.z); v[3] = (short)f2bf(a0.w);
            v[4] = (short)f2bf(a1.x); v[5] = (short)f2bf(a1.y);
            v[6] = (short)f2bf(a1.z); v[7] = (short)f2bf(a1.w);
            xb[kt] = v;
        }

        // -- issue tile i+1 x loads (covered by this tile's compute) --
        if (i + 1 < TILES) {
            const float* p = xrow + (size_t)(i + 1) * (BM * NF);
            #pragma unroll
            for (int kt = 0; kt < 4; ++kt) {
                xa[2 * kt]     = *(const float4*)(p + kt * 32 + q * 8);
                xa[2 * kt + 1] = *(const float4*)(p + kt * 32 + q * 8 + 4);
            }
        }

        // -- layer 1: A = W0 fragment (16x16x32), B = x fragment, C-in = bias --
        f32x4 acc[8];
        #pragma unroll
        for (int gt = 0; gt < 8; ++gt) acc[gt] = *(const f32x4*)&bp[gt * 16 + q * 4];
        #pragma unroll
        for (int kt = 0; kt < 4; ++kt) {
            #pragma unroll
            for (int gt = 0; gt < 8; ++gt) {
                bf16x8 wf = *(const bf16x8*)&w0p[((gt * 4 + kt) * 64 + lane) * 8];
                acc[gt] = __builtin_amdgcn_mfma_f32_16x16x32_bf16(wf, xb[kt], acc[gt], 0, 0, 0);
            }
        }

        // -- relu + pack: layer-1 D layout == 16x16x16 B layout, in-register --
        bf16x4v yb[8];
        #pragma unroll
        for (int gtk = 0; gtk < 8; ++gtk) {
            bf16x4v yv;
            #pragma unroll
            for (int r = 0; r < 4; ++r) {
                float vv = acc[gtk][r];
                vv = vv > 0.f ? vv : 0.f;
                yv[r] = (short)f2bf(vv);
            }
            yb[gtk] = yv;
        }

        // -- layer 2: A = W1 fragment (16x16x16 pair), B = yb, C-in = bias --
        f32x4 acc2[8];
        #pragma unroll
        for (int gt = 0; gt < 8; ++gt) acc2[gt] = *(const f32x4*)&bp[NF + gt * 16 + q * 4];
        #pragma unroll
        for (int ktp = 0; ktp < 4; ++ktp) {
            #pragma unroll
            for (int gt2 = 0; gt2 < 8; ++gt2) {
                bf16x8 wf = *(const bf16x8*)&w1p[((gt2 * 4 + ktp) * 64 + lane) * 8];
                bf16x4v lo = __builtin_shufflevector(wf, wf, 0, 1, 2, 3);
                bf16x4v hi = __builtin_shufflevector(wf, wf, 4, 5, 6, 7);
                acc2[gt2] = __builtin_amdgcn_mfma_f32_16x16x16bf16_1k(lo, yb[2 * ktp],     acc2[gt2], 0, 0, 0);
                acc2[gt2] = __builtin_amdgcn_mfma_f32_16x16x16bf16_1k(hi, yb[2 * ktp + 1], acc2[gt2], 0, 0, 0);
            }
        }

        // -- relu -> global out: coalesced float4 per gt --
        float* op = orow + (size_t)i * (BM * NF);
        #pragma unroll
        for (int gt = 0; gt < 8; ++gt) {
            float4 o;
            float v0 = acc2[gt][0]; o.x = v0 > 0.f ? v0 : 0.f;
            float v1 = acc2[gt][1]; o.y = v1 > 0.f ? v1 : 0.f;
            float v2 = acc2[gt][2]; o.z = v2 > 0.f ? v2 : 0.f;
            float v3 = acc2[gt][3]; o.w = v3 > 0.f ? v3 : 0.f;
            *(float4*)(op + gt * 16 + q * 4) = o;
        }
    }
}

extern "C" void kernel_launch(void* const* d_in, const int* in_sizes, int n_in,
                              void* d_out, int out_size, void* d_ws, size_t ws_size,
                              hipStream_t stream) {
    const float* x = (const float*)d_in[0];
    const float* W = (const float*)d_in[1];
    const float* b = (const float*)d_in[2];
    float* out = (float*)d_out;
    convw_kernel<<<dim3(256), dim3(256), 0, stream>>>(W);
    mlp16_kernel<<<dim3(NM * BLKPM), dim3(512), 0, stream>>>(x, b, out);
}